// Round 1
// baseline (255.356 us; speedup 1.0000x reference)
//
#include <hip/hip_runtime.h>
#include <hip/hip_bf16.h>

#define N_NODES 50000
#define HD 128
#define NTILES (N_NODES / 16)   // 3125, exact
#define NSLICE 64               // edge slices for privatized scatter
#define NQUART 12500            // nodes per LDS quarter (50 KB f32 bins)
#define GRID 256                // one block per CU; capacity-guaranteed residency
#define BLK 512                 // 8 waves/block
#define WPB (BLK / 64)

using short8  = __attribute__((ext_vector_type(8))) short;   // 8 x bf16 bits
using floatx4 = __attribute__((ext_vector_type(4))) float;

__device__ __forceinline__ short f2bf(float f) {
  union { float fp; unsigned u; } un; un.fp = f;
  unsigned u = un.u + 0x7fffu + ((un.u >> 16) & 1u);   // RNE
  return (short)(u >> 16);
}

// Software grid barrier. Safe because grid == 256 blocks x 512 thr x 50KB LDS:
// worst-case packing (2 blocks/CU by LDS+wave limits) still makes ALL blocks
// resident before any can block, so the spin cannot deadlock. Device-scope
// RMWs go to the coherence point (cross-XCD safe); RELEASE on arrive flushes
// this block's L2-resident writes, __threadfence after the spin invalidates
// stale L1/L2 for the whole CU (all waves of this block share them).
__device__ __forceinline__ void gridbar(unsigned* cnt, unsigned target) {
  __syncthreads();                       // drains this block's vmem (waitcnt 0)
  if (threadIdx.x == 0) {
    __hip_atomic_fetch_add(cnt, 1u, __ATOMIC_RELEASE, __HIP_MEMORY_SCOPE_AGENT);
    while (__hip_atomic_fetch_add(cnt, 0u, __ATOMIC_RELAXED,
                                  __HIP_MEMORY_SCOPE_AGENT) < target)
      __builtin_amdgcn_s_sleep(8);
    __threadfence();
  }
  __syncthreads();
}

// ======================= single persistent kernel ===========================
// Phases: A deg-scatter | B dinv | C dinv-gather-scatter | D w & vacc=0 |
//         E MFMA weighted-sum | F head.  5 grid barriers, 1 launch.
__global__ __launch_bounds__(BLK, 2) void k_mega(
    const float* __restrict__ x, const int* __restrict__ src,
    const int* __restrict__ dst, const float* __restrict__ Wf,
    const float* __restrict__ bfeat,
    const float* __restrict__ Wg, const float* __restrict__ bg,
    const float* __restrict__ W1, const float* __restrict__ b1,
    const float* __restrict__ W2, const float* __restrict__ b2,
    float* __restrict__ partial, float* __restrict__ dinv,
    float* __restrict__ w, float* __restrict__ vacc,
    float* __restrict__ out, unsigned* __restrict__ cnt,
    int E, int perSlice) {
  __shared__ __align__(16) char smem[51200];   // 50 KB, reused per phase
  const int tid = threadIdx.x;
  const int bx  = blockIdx.x;
  const int slice = bx & (NSLICE - 1);
  const int qbase = (bx >> 6) * NQUART;
  const int e0 = slice * perSlice;
  const int e1 = min(e0 + perSlice, E);

  // ---- phase A: degree scatter over dst (privatized LDS bins) ----
  {
    float* bins = (float*)smem;
    for (int i = tid; i < NQUART / 4; i += BLK)
      ((float4*)bins)[i] = make_float4(0.f, 0.f, 0.f, 0.f);
    __syncthreads();
    for (int e = e0 + tid; e < e1; e += BLK) {
      int k = dst[e];
      if ((unsigned)(k - qbase) < (unsigned)NQUART)
        atomicAdd(&bins[k - qbase], 1.0f);
    }
    __syncthreads();
    float* op = partial + (size_t)slice * N_NODES + qbase;
    for (int i = tid; i < NQUART / 4; i += BLK)
      ((float4*)op)[i] = ((const float4*)bins)[i];
  }
  gridbar(cnt, GRID * 1);

  // ---- phase B: dinv[n] = rsqrt(1 + sum_s partial[s][n]) ----
  {
    int n = bx * BLK + tid;
    if (n < N_NODES) {
      float s = 1.0f;
      for (int sl = 0; sl < NSLICE; ++sl) s += partial[(size_t)sl * N_NODES + n];
      dinv[n] = rsqrtf(s);
    }
  }
  gridbar(cnt, GRID * 2);

  // ---- phase C: scatter dinv[dst] into bins[src] ----
  {
    float* bins = (float*)smem;
    for (int i = tid; i < NQUART / 4; i += BLK)
      ((float4*)bins)[i] = make_float4(0.f, 0.f, 0.f, 0.f);
    __syncthreads();
    for (int e = e0 + tid; e < e1; e += BLK) {
      int k = src[e];
      if ((unsigned)(k - qbase) < (unsigned)NQUART)
        atomicAdd(&bins[k - qbase], dinv[dst[e]]);
    }
    __syncthreads();
    float* op = partial + (size_t)slice * N_NODES + qbase;
    for (int i = tid; i < NQUART / 4; i += BLK)
      ((float4*)op)[i] = ((const float4*)bins)[i];
  }
  gridbar(cnt, GRID * 3);

  // ---- phase D: w[n] = dinv*(s + dinv); zero vacc ----
  {
    int n = bx * BLK + tid;
    if (n < 2 * HD) vacc[n] = 0.f;
    if (n < N_NODES) {
      float s = 0.0f;
      for (int sl = 0; sl < NSLICE; ++sl) s += partial[(size_t)sl * N_NODES + n];
      float dv = dinv[n];
      w[n] = dv * (s + dv);
    }
  }
  gridbar(cnt, GRID * 4);

  // ---- phase E: vacc[b,h] += sum_n w[n]*relu(x[b,n,:]@Wf + bf)[h] ----
  {
    short* lW = (short*)smem;            // 32 KB of B-fragments
    for (int c = tid; c < 2048; c += BLK) {  // c = (kt*8+t)*64 + lane
      int lane = c & 63, t = (c >> 6) & 7, kt = c >> 9;
      int h = t * 16 + (lane & 15);
      int dbase = kt * 32 + (lane >> 4) * 8;
      short8 v;
#pragma unroll
      for (int j = 0; j < 8; ++j) v[j] = f2bf(Wf[(dbase + j) * HD + h]);
      *(short8*)&lW[c * 8] = v;
    }
    __syncthreads();

    const int lane = tid & 63;
    const int wave = tid >> 6;
    const int col  = lane & 15;
    const int quad = lane >> 4;
    const int gw   = bx * WPB + wave;    // 0..2047
    const int b    = gw & 1;             // wave parity picks batch

    float bias[8];
#pragma unroll
    for (int t = 0; t < 8; ++t) bias[t] = bfeat[t * 16 + col];
    float pv[8];
#pragma unroll
    for (int t = 0; t < 8; ++t) pv[t] = 0.f;

    const float* xb = x + (size_t)b * N_NODES * HD;
    for (int tile = gw >> 1; tile < NTILES; tile += (GRID * WPB) / 2) {
      const int n0 = tile * 16;
      const float* xr = xb + (size_t)(n0 + col) * HD + quad * 8;
      floatx4 acc[8] = {};
#pragma unroll
      for (int kt = 0; kt < 4; ++kt) {
        floatx4 xlo = *(const floatx4*)(xr + kt * 32);
        floatx4 xhi = *(const floatx4*)(xr + kt * 32 + 4);
        short8 a;
#pragma unroll
        for (int j = 0; j < 4; ++j) { a[j] = f2bf(xlo[j]); a[j + 4] = f2bf(xhi[j]); }
#pragma unroll
        for (int t = 0; t < 8; ++t) {
          short8 bfr = *(const short8*)&lW[((kt * 8 + t) * 64 + lane) * 8];
          acc[t] = __builtin_amdgcn_mfma_f32_16x16x32_bf16(a, bfr, acc[t], 0, 0, 0);
        }
      }
      floatx4 w4 = *(const floatx4*)&w[n0 + quad * 4];
#pragma unroll
      for (int t = 0; t < 8; ++t) {
#pragma unroll
        for (int r = 0; r < 4; ++r) {
          float y = acc[t][r] + bias[t];
          pv[t] += fmaxf(y, 0.f) * w4[r];
        }
      }
    }
    __syncthreads();                     // all lW reads done; reuse smem tail
    float* red = (float*)(smem + 32768); // 8 waves x 128 floats = 4 KB
#pragma unroll
    for (int t = 0; t < 8; ++t) {
      float v = pv[t];
      v += __shfl_xor(v, 32, 64);
      v += __shfl_xor(v, 16, 64);
      if (quad == 0) red[wave * 128 + t * 16 + col] = v;
    }
    __syncthreads();
    if (tid < 256) {                     // one atomic per (b,h) per block
      int half = tid >> 7, h = tid & 127;
      float v = red[half * 128 + h] + red[(half + 2) * 128 + h] +
                red[(half + 4) * 128 + h] + red[(half + 6) * 128 + h];
      atomicAdd(&vacc[half * HD + h], v);
    }
  }
  gridbar(cnt, GRID * 5);

  // ---- phase F: tiny head, block 0 only ----
  if (bx == 0) {
    float* pooled = (float*)smem;          // 2*128 floats
    float* zz     = (float*)(smem + 1024); // 2*128 floats
    float* rf     = (float*)(smem + 2048); // 256 floats
    const int b = (tid >> 7) & 1, h = tid & 127;
    if (tid < 256) {
      float acc = 0.f;
      for (int k = 0; k < HD; ++k) acc += vacc[b * HD + k] * Wg[k * HD + h];
      pooled[b * HD + h] = acc * (1.0f / N_NODES) + bg[h];
    }
    __syncthreads();
    if (tid < 256) {
      float acc = 0.f;
      for (int k = 0; k < HD; ++k) acc += pooled[b * HD + k] * W1[k * HD + h];
      zz[b * HD + h] = fmaxf(acc + b1[h], 0.f);
    }
    __syncthreads();
    if (tid < 256) rf[tid] = zz[b * HD + h] * W2[h];
    __syncthreads();
    if (tid < 2) {
      float s = 0.f;
      for (int k = 0; k < HD; ++k) s += rf[tid * HD + k];
      out[tid] = s + b2[0];
    }
  }
}

// =======================  fallback path (device atomics)  ===================
__global__ void k_init(int* __restrict__ deg, float* __restrict__ s,
                       float* __restrict__ vacc) {
  int i = blockIdx.x * 256 + threadIdx.x;
  if (i < N_NODES) { deg[i] = 1; s[i] = 0.f; }
  if (i < 2 * HD) vacc[i] = 0.f;
}
__global__ void k_deg_at(const int* __restrict__ dst, int* __restrict__ deg, int E) {
  int i = blockIdx.x * 256 + threadIdx.x;
  if (i < E) atomicAdd(&deg[dst[i]], 1);
}
__global__ void k_s_at(const int* __restrict__ src, const int* __restrict__ dst,
                       const int* __restrict__ deg, float* __restrict__ s, int E) {
  int i = blockIdx.x * 256 + threadIdx.x;
  if (i < E) {
    float dv = rsqrtf((float)deg[dst[i]]);
    atomicAdd(&s[src[i]], dv);
  }
}
__global__ void k_w_at(const int* __restrict__ deg, float* __restrict__ s) {
  int i = blockIdx.x * 256 + threadIdx.x;
  if (i < N_NODES) {
    float dv = rsqrtf((float)deg[i]);
    s[i] = dv * (s[i] + dv);
  }
}

__global__ __launch_bounds__(256, 2) void k_main(
    const float* __restrict__ x, const float* __restrict__ Wf,
    const float* __restrict__ bfeat, const float* __restrict__ w,
    float* __restrict__ vacc) {
  __shared__ __align__(16) short lW[32 * 64 * 8];   // 32 KB
  const int tid = threadIdx.x;
  for (int c = tid; c < 2048; c += 256) {
    int lane = c & 63, t = (c >> 6) & 7, kt = c >> 9;
    int h = t * 16 + (lane & 15);
    int dbase = kt * 32 + (lane >> 4) * 8;
    short8 v;
#pragma unroll
    for (int j = 0; j < 8; ++j) v[j] = f2bf(Wf[(dbase + j) * HD + h]);
    *(short8*)&lW[c * 8] = v;
  }
  __syncthreads();

  const int lane = tid & 63;
  const int wave = tid >> 6;
  const int col  = lane & 15;
  const int quad = lane >> 4;
  const int b    = blockIdx.y;

  float bias[8];
#pragma unroll
  for (int t = 0; t < 8; ++t) bias[t] = bfeat[t * 16 + col];
  float pv[8];
#pragma unroll
  for (int t = 0; t < 8; ++t) pv[t] = 0.f;

  const float* xb = x + (size_t)b * N_NODES * HD;
  for (int tile = blockIdx.x * 4 + wave; tile < NTILES; tile += gridDim.x * 4) {
    const int n0 = tile * 16;
    const float* xr = xb + (size_t)(n0 + col) * HD + quad * 8;
    floatx4 acc[8] = {};
#pragma unroll
    for (int kt = 0; kt < 4; ++kt) {
      floatx4 xlo = *(const floatx4*)(xr + kt * 32);
      floatx4 xhi = *(const floatx4*)(xr + kt * 32 + 4);
      short8 a;
#pragma unroll
      for (int j = 0; j < 4; ++j) { a[j] = f2bf(xlo[j]); a[j + 4] = f2bf(xhi[j]); }
#pragma unroll
      for (int t = 0; t < 8; ++t) {
        short8 bfr = *(const short8*)&lW[((kt * 8 + t) * 64 + lane) * 8];
        acc[t] = __builtin_amdgcn_mfma_f32_16x16x32_bf16(a, bfr, acc[t], 0, 0, 0);
      }
    }
    floatx4 w4 = *(const floatx4*)&w[n0 + quad * 4];
#pragma unroll
    for (int t = 0; t < 8; ++t) {
#pragma unroll
      for (int r = 0; r < 4; ++r) {
        float y = acc[t][r] + bias[t];
        pv[t] += fmaxf(y, 0.f) * w4[r];
      }
    }
  }

  __syncthreads();
  float* red = (float*)lW;
#pragma unroll
  for (int t = 0; t < 8; ++t) {
    float v = pv[t];
    v += __shfl_xor(v, 32, 64);
    v += __shfl_xor(v, 16, 64);
    if (quad == 0) red[wave * 128 + t * 16 + col] = v;
  }
  __syncthreads();
  if (tid < 128) {
    float v = red[tid] + red[128 + tid] + red[256 + tid] + red[384 + tid];
    atomicAdd(&vacc[b * HD + tid], v);
  }
}

__global__ void k_final(const float* __restrict__ vacc, const float* __restrict__ Wg,
                        const float* __restrict__ bg, const float* __restrict__ W1,
                        const float* __restrict__ b1, const float* __restrict__ W2,
                        const float* __restrict__ b2, float* __restrict__ out) {
  __shared__ float pooled[2][HD];
  __shared__ float z[2][HD];
  __shared__ float red[256];
  const int tid = threadIdx.x;
  const int b = tid >> 7, h = tid & 127;
  float acc = 0.f;
  for (int k = 0; k < HD; ++k) acc += vacc[b * HD + k] * Wg[k * HD + h];
  pooled[b][h] = acc * (1.0f / N_NODES) + bg[h];
  __syncthreads();
  acc = 0.f;
  for (int k = 0; k < HD; ++k) acc += pooled[b][k] * W1[k * HD + h];
  z[b][h] = fmaxf(acc + b1[h], 0.f);
  __syncthreads();
  red[tid] = z[b][h] * W2[h];
  __syncthreads();
  if (tid < 2) {
    float sum = 0.f;
    for (int k = 0; k < HD; ++k) sum += red[tid * HD + k];
    out[tid] = sum + b2[0];
  }
}

extern "C" void kernel_launch(void* const* d_in, const int* in_sizes, int n_in,
                              void* d_out, int out_size, void* d_ws, size_t ws_size,
                              hipStream_t stream) {
  const float* x  = (const float*)d_in[0];
  const int*   ei = (const int*)d_in[1];
  const float* Wf = (const float*)d_in[2];
  const float* bf = (const float*)d_in[3];
  const float* Wg = (const float*)d_in[4];
  const float* bg = (const float*)d_in[5];
  const float* W1 = (const float*)d_in[6];
  const float* b1 = (const float*)d_in[7];
  const float* W2 = (const float*)d_in[8];
  const float* b2 = (const float*)d_in[9];
  float* out = (float*)d_out;

  const int E = in_sizes[1] / 2;
  const int* src = ei;
  const int* dst = ei + E;
  const int perSlice = (E + NSLICE - 1) / NSLICE;

  char* ws = (char*)d_ws;
  const size_t partialB = (size_t)NSLICE * N_NODES * 4;          // 12.8 MB
  const size_t nodeB    = (N_NODES * 4 + 255) & ~(size_t)255;    // 200192 B
  const size_t needed   = partialB + 2 * nodeB + 1024 + 256;

  if (ws_size >= needed) {
    float*    partial = (float*)ws;
    float*    dinv    = (float*)(ws + partialB);
    float*    w       = (float*)(ws + partialB + nodeB);
    float*    vacc    = (float*)(ws + partialB + 2 * nodeB);
    unsigned* cnt     = (unsigned*)(ws + partialB + 2 * nodeB + 1024);

    hipMemsetAsync(cnt, 0, 64, stream);   // barrier counter reset (ws is poisoned)
    k_mega<<<GRID, BLK, 0, stream>>>(x, src, dst, Wf, bf, Wg, bg, W1, b1, W2, b2,
                                     partial, dinv, w, vacc, out, cnt, E, perSlice);
  } else {
    // fallback: device-atomic path
    int*   deg  = (int*)ws;
    float* s    = (float*)(ws + nodeB);
    float* vacc = (float*)(ws + 2 * nodeB);
    k_init<<<(N_NODES + 255) / 256, 256, 0, stream>>>(deg, s, vacc);
    k_deg_at<<<(E + 255) / 256, 256, 0, stream>>>(dst, deg, E);
    k_s_at<<<(E + 255) / 256, 256, 0, stream>>>(src, dst, deg, s, E);
    k_w_at<<<(N_NODES + 255) / 256, 256, 0, stream>>>(deg, s);
    dim3 grid(128, 2);
    k_main<<<grid, 256, 0, stream>>>(x, Wf, bf, s, vacc);
    k_final<<<1, 256, 0, stream>>>(vacc, Wg, bg, W1, b1, W2, b2, out);
  }
  (void)n_in; (void)out_size; (void)ws_size;
}

// Round 2
// 233.343 us; speedup vs baseline: 1.0943x; 1.0943x over previous
//
#include <hip/hip_runtime.h>
#include <hip/hip_bf16.h>

#define N_NODES 50000
#define HD 128
#define NTILES (N_NODES / 16)   // 3125, exact
#define NSLICE 64               // edge slices for privatized scatter
#define NQUART 12500            // nodes per LDS quarter (50 KB f32 bins)
#define GRID 256                // one block per CU; capacity-guaranteed residency
#define BLK 512                 // 8 waves/block
#define WPB (BLK / 64)

using short8  = __attribute__((ext_vector_type(8))) short;   // 8 x bf16 bits
using floatx4 = __attribute__((ext_vector_type(4))) float;

__device__ __forceinline__ short f2bf(float f) {
  union { float fp; unsigned u; } un; un.fp = f;
  unsigned u = un.u + 0x7fffu + ((un.u >> 16) & 1u);   // RNE
  return (short)(u >> 16);
}

// Software grid barrier, load-polling variant.
// R1 lesson: polling with atomic fetch_add RMWs serialized at the coherence
// point and cost ~28 us/barrier (256 pollers' RMWs queue ahead of late
// arrivals). Arrive with ONE release RMW; poll with relaxed agent-scope
// LOADS (scope forces cache-bypass, reads don't serialize ownership);
// acquire fence once on exit. Deadlock-free: 256 blocks x 50KB LDS x 8
// waves -> all blocks resident simultaneously (1 per CU).
__device__ __forceinline__ void gridbar(unsigned* cnt, unsigned target) {
  __syncthreads();                       // all waves' phase work issued+drained
  if (threadIdx.x == 0) {
    __hip_atomic_fetch_add(cnt, 1u, __ATOMIC_RELEASE, __HIP_MEMORY_SCOPE_AGENT);
    while (__hip_atomic_load(cnt, __ATOMIC_RELAXED, __HIP_MEMORY_SCOPE_AGENT)
           < target)
      __builtin_amdgcn_s_sleep(2);
    __builtin_amdgcn_fence(__ATOMIC_ACQUIRE, "agent");
  }
  __syncthreads();
}

// ======================= single persistent kernel ===========================
// Phases: A deg-scatter | B dinv | C dinv-gather-scatter | D w & vacc=0 |
//         E MFMA weighted-sum | F head (last-arriving block only).
// 4 grid barriers + 1 last-arriver detection, 1 launch.
__global__ __launch_bounds__(BLK, 2) void k_mega(
    const float* __restrict__ x, const int* __restrict__ src,
    const int* __restrict__ dst, const float* __restrict__ Wf,
    const float* __restrict__ bfeat,
    const float* __restrict__ Wg, const float* __restrict__ bg,
    const float* __restrict__ W1, const float* __restrict__ b1,
    const float* __restrict__ W2, const float* __restrict__ b2,
    float* __restrict__ partial, float* __restrict__ dinv,
    float* __restrict__ w, float* __restrict__ vacc,
    float* __restrict__ out, unsigned* __restrict__ cnt,
    int E, int perSlice) {
  __shared__ __align__(16) char smem[51200];   // 50 KB, reused per phase
  const int tid = threadIdx.x;
  const int bx  = blockIdx.x;
  const int slice = bx & (NSLICE - 1);
  const int qbase = (bx >> 6) * NQUART;
  const int e0 = slice * perSlice;
  const int e1 = min(e0 + perSlice, E);

  // ---- phase A: degree scatter over dst (privatized LDS bins) ----
  {
    float* bins = (float*)smem;
    for (int i = tid; i < NQUART / 4; i += BLK)
      ((float4*)bins)[i] = make_float4(0.f, 0.f, 0.f, 0.f);
    __syncthreads();
    for (int e = e0 + tid; e < e1; e += BLK) {
      int k = dst[e];
      if ((unsigned)(k - qbase) < (unsigned)NQUART)
        atomicAdd(&bins[k - qbase], 1.0f);
    }
    __syncthreads();
    float* op = partial + (size_t)slice * N_NODES + qbase;
    for (int i = tid; i < NQUART / 4; i += BLK)
      ((float4*)op)[i] = ((const float4*)bins)[i];
  }
  gridbar(cnt, GRID * 1);

  // ---- phase B: dinv[n] = rsqrt(1 + sum_s partial[s][n]) ----
  {
    int n = bx * BLK + tid;
    if (n < N_NODES) {
      float s = 1.0f;
      for (int sl = 0; sl < NSLICE; ++sl) s += partial[(size_t)sl * N_NODES + n];
      dinv[n] = rsqrtf(s);
    }
  }
  gridbar(cnt, GRID * 2);

  // ---- phase C: scatter dinv[dst] into bins[src] ----
  {
    float* bins = (float*)smem;
    for (int i = tid; i < NQUART / 4; i += BLK)
      ((float4*)bins)[i] = make_float4(0.f, 0.f, 0.f, 0.f);
    __syncthreads();
    for (int e = e0 + tid; e < e1; e += BLK) {
      int k = src[e];
      if ((unsigned)(k - qbase) < (unsigned)NQUART)
        atomicAdd(&bins[k - qbase], dinv[dst[e]]);
    }
    __syncthreads();
    float* op = partial + (size_t)slice * N_NODES + qbase;
    for (int i = tid; i < NQUART / 4; i += BLK)
      ((float4*)op)[i] = ((const float4*)bins)[i];
  }
  gridbar(cnt, GRID * 3);

  // ---- phase D: w[n] = dinv*(s + dinv); zero vacc ----
  {
    int n = bx * BLK + tid;
    if (n < 2 * HD) vacc[n] = 0.f;
    if (n < N_NODES) {
      float s = 0.0f;
      for (int sl = 0; sl < NSLICE; ++sl) s += partial[(size_t)sl * N_NODES + n];
      float dv = dinv[n];
      w[n] = dv * (s + dv);
    }
  }
  gridbar(cnt, GRID * 4);

  // ---- phase E: vacc[b,h] += sum_n w[n]*relu(x[b,n,:]@Wf + bf)[h] ----
  {
    short* lW = (short*)smem;            // 32 KB of B-fragments
    for (int c = tid; c < 2048; c += BLK) {  // c = (kt*8+t)*64 + lane
      int lane = c & 63, t = (c >> 6) & 7, kt = c >> 9;
      int h = t * 16 + (lane & 15);
      int dbase = kt * 32 + (lane >> 4) * 8;
      short8 v;
#pragma unroll
      for (int j = 0; j < 8; ++j) v[j] = f2bf(Wf[(dbase + j) * HD + h]);
      *(short8*)&lW[c * 8] = v;
    }
    __syncthreads();

    const int lane = tid & 63;
    const int wave = tid >> 6;
    const int col  = lane & 15;
    const int quad = lane >> 4;
    const int gw   = bx * WPB + wave;    // 0..2047
    const int b    = gw & 1;             // wave parity picks batch

    float bias[8];
#pragma unroll
    for (int t = 0; t < 8; ++t) bias[t] = bfeat[t * 16 + col];
    float pv[8];
#pragma unroll
    for (int t = 0; t < 8; ++t) pv[t] = 0.f;

    const float* xb = x + (size_t)b * N_NODES * HD;
    for (int tile = gw >> 1; tile < NTILES; tile += (GRID * WPB) / 2) {
      const int n0 = tile * 16;
      const float* xr = xb + (size_t)(n0 + col) * HD + quad * 8;
      floatx4 acc[8] = {};
#pragma unroll
      for (int kt = 0; kt < 4; ++kt) {
        floatx4 xlo = *(const floatx4*)(xr + kt * 32);
        floatx4 xhi = *(const floatx4*)(xr + kt * 32 + 4);
        short8 a;
#pragma unroll
        for (int j = 0; j < 4; ++j) { a[j] = f2bf(xlo[j]); a[j + 4] = f2bf(xhi[j]); }
#pragma unroll
        for (int t = 0; t < 8; ++t) {
          short8 bfr = *(const short8*)&lW[((kt * 8 + t) * 64 + lane) * 8];
          acc[t] = __builtin_amdgcn_mfma_f32_16x16x32_bf16(a, bfr, acc[t], 0, 0, 0);
        }
      }
      floatx4 w4 = *(const floatx4*)&w[n0 + quad * 4];
#pragma unroll
      for (int t = 0; t < 8; ++t) {
#pragma unroll
        for (int r = 0; r < 4; ++r) {
          float y = acc[t][r] + bias[t];
          pv[t] += fmaxf(y, 0.f) * w4[r];
        }
      }
    }
    __syncthreads();                     // all lW reads done; reuse smem tail
    float* red = (float*)(smem + 32768); // 8 waves x 128 floats = 4 KB
#pragma unroll
    for (int t = 0; t < 8; ++t) {
      float v = pv[t];
      v += __shfl_xor(v, 32, 64);
      v += __shfl_xor(v, 16, 64);
      if (quad == 0) red[wave * 128 + t * 16 + col] = v;
    }
    __syncthreads();
    if (tid < 256) {                     // one atomic per (b,h) per block
      int half = tid >> 7, h = tid & 127;
      float v = red[half * 128 + h] + red[(half + 2) * 128 + h] +
                red[(half + 4) * 128 + h] + red[(half + 6) * 128 + h];
      atomicAdd(&vacc[half * HD + h], v);
    }
  }

  // ---- phase E done: LAST arriving block (and only it) runs the head. ----
  // 255 blocks pay one RMW and exit; no spin, no 5th barrier.
  __syncthreads();
  __shared__ int lastFlag;
  if (tid == 0) {
    unsigned old = __hip_atomic_fetch_add(cnt, 1u, __ATOMIC_ACQ_REL,
                                          __HIP_MEMORY_SCOPE_AGENT);
    lastFlag = (old == GRID * 5 - 1) ? 1 : 0;
  }
  __syncthreads();
  if (!lastFlag) return;
  __threadfence();                       // see all blocks' vacc atomics

  // ---- phase F: tiny head ----
  {
    float* pooled = (float*)smem;          // 2*128 floats
    float* zz     = (float*)(smem + 1024); // 2*128 floats
    float* rf     = (float*)(smem + 2048); // 256 floats
    const int b = (tid >> 7) & 1, h = tid & 127;
    if (tid < 256) {
      float acc = 0.f;
      for (int k = 0; k < HD; ++k) acc += vacc[b * HD + k] * Wg[k * HD + h];
      pooled[b * HD + h] = acc * (1.0f / N_NODES) + bg[h];
    }
    __syncthreads();
    if (tid < 256) {
      float acc = 0.f;
      for (int k = 0; k < HD; ++k) acc += pooled[b * HD + k] * W1[k * HD + h];
      zz[b * HD + h] = fmaxf(acc + b1[h], 0.f);
    }
    __syncthreads();
    if (tid < 256) rf[tid] = zz[b * HD + h] * W2[h];
    __syncthreads();
    if (tid < 2) {
      float s = 0.f;
      for (int k = 0; k < HD; ++k) s += rf[tid * HD + k];
      out[tid] = s + b2[0];
    }
  }
}

// =======================  fallback path (device atomics)  ===================
__global__ void k_init(int* __restrict__ deg, float* __restrict__ s,
                       float* __restrict__ vacc) {
  int i = blockIdx.x * 256 + threadIdx.x;
  if (i < N_NODES) { deg[i] = 1; s[i] = 0.f; }
  if (i < 2 * HD) vacc[i] = 0.f;
}
__global__ void k_deg_at(const int* __restrict__ dst, int* __restrict__ deg, int E) {
  int i = blockIdx.x * 256 + threadIdx.x;
  if (i < E) atomicAdd(&deg[dst[i]], 1);
}
__global__ void k_s_at(const int* __restrict__ src, const int* __restrict__ dst,
                       const int* __restrict__ deg, float* __restrict__ s, int E) {
  int i = blockIdx.x * 256 + threadIdx.x;
  if (i < E) {
    float dv = rsqrtf((float)deg[dst[i]]);
    atomicAdd(&s[src[i]], dv);
  }
}
__global__ void k_w_at(const int* __restrict__ deg, float* __restrict__ s) {
  int i = blockIdx.x * 256 + threadIdx.x;
  if (i < N_NODES) {
    float dv = rsqrtf((float)deg[i]);
    s[i] = dv * (s[i] + dv);
  }
}

__global__ __launch_bounds__(256, 2) void k_main(
    const float* __restrict__ x, const float* __restrict__ Wf,
    const float* __restrict__ bfeat, const float* __restrict__ w,
    float* __restrict__ vacc) {
  __shared__ __align__(16) short lW[32 * 64 * 8];   // 32 KB
  const int tid = threadIdx.x;
  for (int c = tid; c < 2048; c += 256) {
    int lane = c & 63, t = (c >> 6) & 7, kt = c >> 9;
    int h = t * 16 + (lane & 15);
    int dbase = kt * 32 + (lane >> 4) * 8;
    short8 v;
#pragma unroll
    for (int j = 0; j < 8; ++j) v[j] = f2bf(Wf[(dbase + j) * HD + h]);
    *(short8*)&lW[c * 8] = v;
  }
  __syncthreads();

  const int lane = tid & 63;
  const int wave = tid >> 6;
  const int col  = lane & 15;
  const int quad = lane >> 4;
  const int b    = blockIdx.y;

  float bias[8];
#pragma unroll
  for (int t = 0; t < 8; ++t) bias[t] = bfeat[t * 16 + col];
  float pv[8];
#pragma unroll
  for (int t = 0; t < 8; ++t) pv[t] = 0.f;

  const float* xb = x + (size_t)b * N_NODES * HD;
  for (int tile = blockIdx.x * 4 + wave; tile < NTILES; tile += gridDim.x * 4) {
    const int n0 = tile * 16;
    const float* xr = xb + (size_t)(n0 + col) * HD + quad * 8;
    floatx4 acc[8] = {};
#pragma unroll
    for (int kt = 0; kt < 4; ++kt) {
      floatx4 xlo = *(const floatx4*)(xr + kt * 32);
      floatx4 xhi = *(const floatx4*)(xr + kt * 32 + 4);
      short8 a;
#pragma unroll
      for (int j = 0; j < 4; ++j) { a[j] = f2bf(xlo[j]); a[j + 4] = f2bf(xhi[j]); }
#pragma unroll
      for (int t = 0; t < 8; ++t) {
        short8 bfr = *(const short8*)&lW[((kt * 8 + t) * 64 + lane) * 8];
        acc[t] = __builtin_amdgcn_mfma_f32_16x16x32_bf16(a, bfr, acc[t], 0, 0, 0);
      }
    }
    floatx4 w4 = *(const floatx4*)&w[n0 + quad * 4];
#pragma unroll
    for (int t = 0; t < 8; ++t) {
#pragma unroll
      for (int r = 0; r < 4; ++r) {
        float y = acc[t][r] + bias[t];
        pv[t] += fmaxf(y, 0.f) * w4[r];
      }
    }
  }

  __syncthreads();
  float* red = (float*)lW;
#pragma unroll
  for (int t = 0; t < 8; ++t) {
    float v = pv[t];
    v += __shfl_xor(v, 32, 64);
    v += __shfl_xor(v, 16, 64);
    if (quad == 0) red[wave * 128 + t * 16 + col] = v;
  }
  __syncthreads();
  if (tid < 128) {
    float v = red[tid] + red[128 + tid] + red[256 + tid] + red[384 + tid];
    atomicAdd(&vacc[b * HD + tid], v);
  }
}

__global__ void k_final(const float* __restrict__ vacc, const float* __restrict__ Wg,
                        const float* __restrict__ bg, const float* __restrict__ W1,
                        const float* __restrict__ b1, const float* __restrict__ W2,
                        const float* __restrict__ b2, float* __restrict__ out) {
  __shared__ float pooled[2][HD];
  __shared__ float z[2][HD];
  __shared__ float red[256];
  const int tid = threadIdx.x;
  const int b = tid >> 7, h = tid & 127;
  float acc = 0.f;
  for (int k = 0; k < HD; ++k) acc += vacc[b * HD + k] * Wg[k * HD + h];
  pooled[b][h] = acc * (1.0f / N_NODES) + bg[h];
  __syncthreads();
  acc = 0.f;
  for (int k = 0; k < HD; ++k) acc += pooled[b][k] * W1[k * HD + h];
  z[b][h] = fmaxf(acc + b1[h], 0.f);
  __syncthreads();
  red[tid] = z[b][h] * W2[h];
  __syncthreads();
  if (tid < 2) {
    float sum = 0.f;
    for (int k = 0; k < HD; ++k) sum += red[tid * HD + k];
    out[tid] = sum + b2[0];
  }
}

extern "C" void kernel_launch(void* const* d_in, const int* in_sizes, int n_in,
                              void* d_out, int out_size, void* d_ws, size_t ws_size,
                              hipStream_t stream) {
  const float* x  = (const float*)d_in[0];
  const int*   ei = (const int*)d_in[1];
  const float* Wf = (const float*)d_in[2];
  const float* bf = (const float*)d_in[3];
  const float* Wg = (const float*)d_in[4];
  const float* bg = (const float*)d_in[5];
  const float* W1 = (const float*)d_in[6];
  const float* b1 = (const float*)d_in[7];
  const float* W2 = (const float*)d_in[8];
  const float* b2 = (const float*)d_in[9];
  float* out = (float*)d_out;

  const int E = in_sizes[1] / 2;
  const int* src = ei;
  const int* dst = ei + E;
  const int perSlice = (E + NSLICE - 1) / NSLICE;

  char* ws = (char*)d_ws;
  const size_t partialB = (size_t)NSLICE * N_NODES * 4;          // 12.8 MB
  const size_t nodeB    = (N_NODES * 4 + 255) & ~(size_t)255;    // 200192 B
  const size_t needed   = partialB + 2 * nodeB + 1024 + 256;

  if (ws_size >= needed) {
    float*    partial = (float*)ws;
    float*    dinv    = (float*)(ws + partialB);
    float*    w       = (float*)(ws + partialB + nodeB);
    float*    vacc    = (float*)(ws + partialB + 2 * nodeB);
    unsigned* cnt     = (unsigned*)(ws + partialB + 2 * nodeB + 1024);

    hipMemsetAsync(cnt, 0, 64, stream);   // barrier counter reset (ws is poisoned)
    k_mega<<<GRID, BLK, 0, stream>>>(x, src, dst, Wf, bf, Wg, bg, W1, b1, W2, b2,
                                     partial, dinv, w, vacc, out, cnt, E, perSlice);
  } else {
    // fallback: device-atomic path
    int*   deg  = (int*)ws;
    float* s    = (float*)(ws + nodeB);
    float* vacc = (float*)(ws + 2 * nodeB);
    k_init<<<(N_NODES + 255) / 256, 256, 0, stream>>>(deg, s, vacc);
    k_deg_at<<<(E + 255) / 256, 256, 0, stream>>>(dst, deg, E);
    k_s_at<<<(E + 255) / 256, 256, 0, stream>>>(src, dst, deg, s, E);
    k_w_at<<<(N_NODES + 255) / 256, 256, 0, stream>>>(deg, s);
    dim3 grid(128, 2);
    k_main<<<grid, 256, 0, stream>>>(x, Wf, bf, s, vacc);
    k_final<<<1, 256, 0, stream>>>(vacc, Wg, bg, W1, b1, W2, b2, out);
  }
  (void)n_in; (void)out_size; (void)ws_size;
}

// Round 3
// 176.503 us; speedup vs baseline: 1.4468x; 1.3220x over previous
//
#include <hip/hip_runtime.h>
#include <hip/hip_bf16.h>

#define N_NODES 50000
#define HD 128
#define NTILES (N_NODES / 16)   // 3125, exact
#define NSLICE 64               // edge slices for privatized scatter
#define NQUART 12500            // nodes per LDS quarter (50 KB f32 bins)
#define NG 8                    // vacc privatization groups (k_main)

using short8  = __attribute__((ext_vector_type(8))) short;   // 8 x bf16 bits
using floatx4 = __attribute__((ext_vector_type(4))) float;

__device__ __forceinline__ short f2bf(float f) {
  union { float fp; unsigned u; } un; un.fp = f;
  unsigned u = un.u + 0x7fffu + ((un.u >> 16) & 1u);   // RNE
  return (short)(u >> 16);
}

// =======================  edge phase (no device atomics)  ===================
// partial[s][n] accumulates per-slice sums; block (slice, quarter) owns
// 12500-node LDS bins and writes them back non-atomically.
// R3: key stream vectorized int4 (4 edges/lane/iter) with alignment guards.
template <bool GATHER>
__global__ __launch_bounds__(1024) void k_scatter(
    const int* __restrict__ keys, const int* __restrict__ other,
    const float* __restrict__ dinv, float* __restrict__ partial,
    int E, int perSlice) {
  __shared__ __align__(16) float bins[NQUART];
  const int tid = threadIdx.x;
  for (int i = tid; i < NQUART / 4; i += 1024)
    ((float4*)bins)[i] = make_float4(0.f, 0.f, 0.f, 0.f);
  __syncthreads();

  const int slice = blockIdx.x;
  const int base  = blockIdx.y * NQUART;
  const int e0 = slice * perSlice;
  const int e1 = min(e0 + perSlice, E);
  const int eA = min((e0 + 3) & ~3, e1);   // 16B-aligned body start
  const int eB = max(e1 & ~3, eA);         // aligned body end

  // scalar head
  for (int e = e0 + tid; e < eA; e += 1024) {
    int k = keys[e];
    if ((unsigned)(k - base) < (unsigned)NQUART) {
      float v = GATHER ? dinv[other[e]] : 1.0f;
      atomicAdd(&bins[k - base], v);
    }
  }
  // int4 body
  const int n4 = (eB - eA) >> 2;
  const int4* k4 = (const int4*)(keys + eA);
  for (int i = tid; i < n4; i += 1024) {
    int4 kk = k4[i];
    int eb = eA + i * 4;
#pragma unroll
    for (int j = 0; j < 4; ++j) {
      int k = (&kk.x)[j];
      if ((unsigned)(k - base) < (unsigned)NQUART) {
        float v = GATHER ? dinv[other[eb + j]] : 1.0f;
        atomicAdd(&bins[k - base], v);
      }
    }
  }
  // scalar tail
  for (int e = eB + tid; e < e1; e += 1024) {
    int k = keys[e];
    if ((unsigned)(k - base) < (unsigned)NQUART) {
      float v = GATHER ? dinv[other[e]] : 1.0f;
      atomicAdd(&bins[k - base], v);
    }
  }
  __syncthreads();

  float* out = partial + (size_t)slice * N_NODES + base;
  for (int i = tid; i < NQUART / 4; i += 1024)
    ((float4*)out)[i] = ((const float4*)bins)[i];
}

// dinv[n] = rsqrt(1 + sum_s partial[s][n])  (self-loop -> +1); zero vaccp
__global__ void k_merge_deg(const float* __restrict__ partial,
                            float* __restrict__ dinv,
                            float* __restrict__ vaccp) {
  int n = blockIdx.x * 256 + threadIdx.x;
  if (n < NG * 2 * HD) vaccp[n] = 0.f;
  if (n >= N_NODES) return;
  float s = 1.0f;
#pragma unroll
  for (int sl = 0; sl < NSLICE; ++sl) s += partial[(size_t)sl * N_NODES + n];
  dinv[n] = rsqrtf(s);
}

// w[n] = dinv[n] * (sum_s partial[s][n] + dinv[n])
__global__ void k_merge_w(const float* __restrict__ partial,
                          const float* __restrict__ dinv,
                          float* __restrict__ w) {
  int n = blockIdx.x * 256 + threadIdx.x;
  if (n >= N_NODES) return;
  float s = 0.0f;
#pragma unroll
  for (int sl = 0; sl < NSLICE; ++sl) s += partial[(size_t)sl * N_NODES + n];
  float dv = dinv[n];
  w[n] = dv * (s + dv);
}

// ---- main: vaccp[g,b,h] += sum_n w[n] * relu(x[b,n,:] @ W_feat + b_feat)[h]
// R3: grid (512,2) = 4 blocks/CU, 16 waves/CU for the 51.2 MB x-stream.
__global__ __launch_bounds__(256, 2) void k_main(
    const float* __restrict__ x, const float* __restrict__ Wf,
    const float* __restrict__ bfeat, const float* __restrict__ w,
    float* __restrict__ vaccp) {
  // B-fragments of W_feat, pre-swizzled: frag (kt,t), lane-contiguous 16B
  __shared__ __align__(16) short lW[32 * 64 * 8];   // 32 KB
  const int tid = threadIdx.x;
  for (int c = tid; c < 2048; c += 256) {           // c = (kt*8+t)*64 + lane
    int lane = c & 63, t = (c >> 6) & 7, kt = c >> 9;
    int h = t * 16 + (lane & 15);
    int dbase = kt * 32 + (lane >> 4) * 8;
    short8 v;
#pragma unroll
    for (int j = 0; j < 8; ++j) v[j] = f2bf(Wf[(dbase + j) * HD + h]);
    *(short8*)&lW[c * 8] = v;
  }
  __syncthreads();

  const int lane = tid & 63;
  const int wave = tid >> 6;
  const int col  = lane & 15;
  const int quad = lane >> 4;
  const int b    = blockIdx.y;
  const int g    = blockIdx.x & (NG - 1);

  float bias[8];
#pragma unroll
  for (int t = 0; t < 8; ++t) bias[t] = bfeat[t * 16 + col];

  float pv[8];
#pragma unroll
  for (int t = 0; t < 8; ++t) pv[t] = 0.f;

  const float* xb = x + (size_t)b * N_NODES * HD;
  for (int tile = blockIdx.x * 4 + wave; tile < NTILES; tile += gridDim.x * 4) {
    const int n0 = tile * 16;
    const float* xr = xb + (size_t)(n0 + col) * HD + quad * 8;  // A row = col
    floatx4 acc[8] = {};
#pragma unroll
    for (int kt = 0; kt < 4; ++kt) {
      floatx4 xlo = *(const floatx4*)(xr + kt * 32);
      floatx4 xhi = *(const floatx4*)(xr + kt * 32 + 4);
      short8 a;
#pragma unroll
      for (int j = 0; j < 4; ++j) { a[j] = f2bf(xlo[j]); a[j + 4] = f2bf(xhi[j]); }
#pragma unroll
      for (int t = 0; t < 8; ++t) {
        short8 bf = *(const short8*)&lW[((kt * 8 + t) * 64 + lane) * 8];
        acc[t] = __builtin_amdgcn_mfma_f32_16x16x32_bf16(a, bf, acc[t], 0, 0, 0);
      }
    }
    floatx4 w4 = *(const floatx4*)&w[n0 + quad * 4];  // D rows = quad*4 + r
#pragma unroll
    for (int t = 0; t < 8; ++t) {
#pragma unroll
      for (int r = 0; r < 4; ++r) {
        float y = acc[t][r] + bias[t];
        pv[t] += fmaxf(y, 0.f) * w4[r];
      }
    }
  }

  // cross-wave LDS reduce, then ONE atomic per (g,b,h) per block
  __syncthreads();                     // all lW reads done; reuse as scratch
  float* red = (float*)lW;             // need 4*128 floats
#pragma unroll
  for (int t = 0; t < 8; ++t) {
    float v = pv[t];
    v += __shfl_xor(v, 32, 64);
    v += __shfl_xor(v, 16, 64);
    if (quad == 0) red[wave * 128 + t * 16 + col] = v;
  }
  __syncthreads();
  if (tid < 128) {
    float v = red[tid] + red[128 + tid] + red[256 + tid] + red[384 + tid];
    atomicAdd(&vaccp[(g * 2 + b) * HD + tid], v);
  }
}

// ---- tiny head ----
__global__ void k_final(const float* __restrict__ vaccp, const float* __restrict__ Wg,
                        const float* __restrict__ bg, const float* __restrict__ W1,
                        const float* __restrict__ b1, const float* __restrict__ W2,
                        const float* __restrict__ b2, float* __restrict__ out) {
  __shared__ float vsum[2 * HD];
  __shared__ float pooled[2][HD];
  __shared__ float z[2][HD];
  __shared__ float red[256];
  const int tid = threadIdx.x;
  const int b = tid >> 7, h = tid & 127;
  {
    float v = 0.f;
#pragma unroll
    for (int g = 0; g < NG; ++g) v += vaccp[g * 2 * HD + tid];
    vsum[tid] = v;
  }
  __syncthreads();
  float acc = 0.f;
  for (int k = 0; k < HD; ++k) acc += vsum[b * HD + k] * Wg[k * HD + h];
  pooled[b][h] = acc * (1.0f / N_NODES) + bg[h];
  __syncthreads();
  acc = 0.f;
  for (int k = 0; k < HD; ++k) acc += pooled[b][k] * W1[k * HD + h];
  z[b][h] = fmaxf(acc + b1[h], 0.f);
  __syncthreads();
  red[tid] = z[b][h] * W2[h];
  __syncthreads();
  if (tid < 2) {
    float sum = 0.f;
    for (int k = 0; k < HD; ++k) sum += red[tid * HD + k];
    out[tid] = sum + b2[0];
  }
}

// =======================  fallback edge phase (device atomics)  =============
__global__ void k_init(int* __restrict__ deg, float* __restrict__ s,
                       float* __restrict__ vacc) {
  int i = blockIdx.x * 256 + threadIdx.x;
  if (i < N_NODES) { deg[i] = 1; s[i] = 0.f; }
  if (i < NG * 2 * HD) vacc[i] = 0.f;
}
__global__ void k_deg_at(const int* __restrict__ dst, int* __restrict__ deg, int E) {
  int i = blockIdx.x * 256 + threadIdx.x;
  if (i < E) atomicAdd(&deg[dst[i]], 1);
}
__global__ void k_s_at(const int* __restrict__ src, const int* __restrict__ dst,
                       const int* __restrict__ deg, float* __restrict__ s, int E) {
  int i = blockIdx.x * 256 + threadIdx.x;
  if (i < E) {
    float dv = rsqrtf((float)deg[dst[i]]);
    atomicAdd(&s[src[i]], dv);
  }
}
__global__ void k_w_at(const int* __restrict__ deg, float* __restrict__ s) {
  int i = blockIdx.x * 256 + threadIdx.x;
  if (i < N_NODES) {
    float dv = rsqrtf((float)deg[i]);
    s[i] = dv * (s[i] + dv);
  }
}

extern "C" void kernel_launch(void* const* d_in, const int* in_sizes, int n_in,
                              void* d_out, int out_size, void* d_ws, size_t ws_size,
                              hipStream_t stream) {
  const float* x  = (const float*)d_in[0];
  const int*   ei = (const int*)d_in[1];
  const float* Wf = (const float*)d_in[2];
  const float* bf = (const float*)d_in[3];
  const float* Wg = (const float*)d_in[4];
  const float* bg = (const float*)d_in[5];
  const float* W1 = (const float*)d_in[6];
  const float* b1 = (const float*)d_in[7];
  const float* W2 = (const float*)d_in[8];
  const float* b2 = (const float*)d_in[9];
  float* out = (float*)d_out;

  const int E = in_sizes[1] / 2;
  const int* src = ei;
  const int* dst = ei + E;
  const int perSlice = (E + NSLICE - 1) / NSLICE;

  char* ws = (char*)d_ws;
  const size_t partialB = (size_t)NSLICE * N_NODES * 4;          // 12.8 MB
  const size_t nodeB    = (N_NODES * 4 + 255) & ~(size_t)255;    // 200192 B
  const size_t vaccB    = NG * 2 * HD * 4;                       // 8 KB
  const size_t needed   = partialB + 2 * nodeB + vaccB;

  if (ws_size >= needed) {
    float* partial = (float*)ws;
    float* dinv    = (float*)(ws + partialB);
    float* w       = (float*)(ws + partialB + nodeB);
    float* vaccp   = (float*)(ws + partialB + 2 * nodeB);

    dim3 sg(NSLICE, N_NODES / NQUART);   // 64 x 4 = 256 blocks
    k_scatter<false><<<sg, 1024, 0, stream>>>(dst, nullptr, nullptr, partial, E, perSlice);
    k_merge_deg<<<(N_NODES + 255) / 256, 256, 0, stream>>>(partial, dinv, vaccp);
    k_scatter<true><<<sg, 1024, 0, stream>>>(src, dst, dinv, partial, E, perSlice);
    k_merge_w<<<(N_NODES + 255) / 256, 256, 0, stream>>>(partial, dinv, w);
    dim3 grid(512, 2);                   // 1024 blocks, 4/CU, 16 waves/CU
    k_main<<<grid, 256, 0, stream>>>(x, Wf, bf, w, vaccp);
    k_final<<<1, 256, 0, stream>>>(vaccp, Wg, bg, W1, b1, W2, b2, out);
  } else {
    // fallback: device-atomic path
    int*   deg  = (int*)ws;
    float* s    = (float*)(ws + nodeB);
    float* vaccp = (float*)(ws + 2 * nodeB);
    k_init<<<(N_NODES + 255) / 256, 256, 0, stream>>>(deg, s, vaccp);
    k_deg_at<<<(E + 255) / 256, 256, 0, stream>>>(dst, deg, E);
    k_s_at<<<(E + 255) / 256, 256, 0, stream>>>(src, dst, deg, s, E);
    k_w_at<<<(N_NODES + 255) / 256, 256, 0, stream>>>(deg, s);
    dim3 grid(512, 2);
    k_main<<<grid, 256, 0, stream>>>(x, Wf, bf, s, vaccp);
    k_final<<<1, 256, 0, stream>>>(vaccp, Wg, bg, W1, b1, W2, b2, out);
  }
  (void)n_in; (void)out_size; (void)ws_size;
}

// Round 4
// 159.124 us; speedup vs baseline: 1.6048x; 1.1092x over previous
//
#include <hip/hip_runtime.h>
#include <hip/hip_bf16.h>

#define N_NODES 50000
#define HD 128
#define NTILES (N_NODES / 16)   // 3125, exact
#define NSLICE 64               // edge slices for privatized scatter
#define NQUART 12500            // nodes per LDS quarter (50 KB f32 bins)

using short8  = __attribute__((ext_vector_type(8))) short;   // 8 x bf16 bits
using floatx4 = __attribute__((ext_vector_type(4))) float;

__device__ __forceinline__ short f2bf(float f) {
  union { float fp; unsigned u; } un; un.fp = f;
  unsigned u = un.u + 0x7fffu + ((un.u >> 16) & 1u);   // RNE
  return (short)(u >> 16);
}

// =======================  fast edge phase (no device atomics)  ==============
// R0-verbatim. partial[s][n] accumulates per-slice sums; block (slice,quarter)
// owns 12500-node LDS bins and writes them back non-atomically.
template <bool GATHER>
__global__ __launch_bounds__(1024) void k_scatter(
    const int* __restrict__ keys, const int* __restrict__ other,
    const float* __restrict__ dinv, float* __restrict__ partial,
    int E, int perSlice) {
  __shared__ __align__(16) float bins[NQUART];
  const int tid = threadIdx.x;
  for (int i = tid; i < NQUART / 4; i += 1024)
    ((float4*)bins)[i] = make_float4(0.f, 0.f, 0.f, 0.f);
  __syncthreads();

  const int slice = blockIdx.x;
  const int base  = blockIdx.y * NQUART;
  const int e0 = slice * perSlice;
  const int e1 = min(e0 + perSlice, E);
  for (int e = e0 + tid; e < e1; e += 1024) {
    int k = keys[e];
    if ((unsigned)(k - base) < (unsigned)NQUART) {
      float v = GATHER ? dinv[other[e]] : 1.0f;
      atomicAdd(&bins[k - base], v);           // ds_add_f32, LDS-local
    }
  }
  __syncthreads();

  float* out = partial + (size_t)slice * N_NODES + base;
  for (int i = tid; i < NQUART / 4; i += 1024)
    ((float4*)out)[i] = ((const float4*)bins)[i];
}

// dinv[n] = rsqrt(1 + sum_s partial[s][n])      (self-loop -> +1)  [R0-verbatim]
__global__ void k_merge_deg(const float* __restrict__ partial,
                            float* __restrict__ dinv) {
  int n = blockIdx.x * 256 + threadIdx.x;
  if (n >= N_NODES) return;
  float s = 1.0f;
  for (int sl = 0; sl < NSLICE; ++sl) s += partial[(size_t)sl * N_NODES + n];
  dinv[n] = rsqrtf(s);
}

// w[n] = dinv[n] * (sum_s partial[s][n] + dinv[n]); zero vacc and cnt
__global__ void k_merge_w(const float* __restrict__ partial,
                          const float* __restrict__ dinv,
                          float* __restrict__ w, float* __restrict__ vacc,
                          unsigned* __restrict__ cnt) {
  int n = blockIdx.x * 256 + threadIdx.x;
  if (n < 2 * HD) vacc[n] = 0.f;
  if (n == 0) cnt[0] = 0u;
  if (n >= N_NODES) return;
  float s = 0.0f;
  for (int sl = 0; sl < NSLICE; ++sl) s += partial[(size_t)sl * N_NODES + n];
  float dv = dinv[n];
  w[n] = dv * (s + dv);
}

// =======================  fallback edge phase (device atomics)  =============
__global__ void k_init(int* __restrict__ deg, float* __restrict__ s,
                       float* __restrict__ vacc, unsigned* __restrict__ cnt) {
  int i = blockIdx.x * 256 + threadIdx.x;
  if (i < N_NODES) { deg[i] = 1; s[i] = 0.f; }
  if (i < 2 * HD) vacc[i] = 0.f;
  if (i == 0) cnt[0] = 0u;
}
__global__ void k_deg_at(const int* __restrict__ dst, int* __restrict__ deg, int E) {
  int i = blockIdx.x * 256 + threadIdx.x;
  if (i < E) atomicAdd(&deg[dst[i]], 1);
}
__global__ void k_s_at(const int* __restrict__ src, const int* __restrict__ dst,
                       const int* __restrict__ deg, float* __restrict__ s, int E) {
  int i = blockIdx.x * 256 + threadIdx.x;
  if (i < E) {
    float dv = rsqrtf((float)deg[dst[i]]);
    atomicAdd(&s[src[i]], dv);
  }
}
__global__ void k_w_at(const int* __restrict__ deg, float* __restrict__ s) {
  int i = blockIdx.x * 256 + threadIdx.x;
  if (i < N_NODES) {
    float dv = rsqrtf((float)deg[i]);
    s[i] = dv * (s[i] + dv);
  }
}

// ---- main: vacc[b,h] = sum_n w[n] * relu(x[b,n,:] @ W_feat + b_feat)[h] ----
// R4: grid (256,2) = 2 blocks/CU, 8 waves/CU (R0 had 1 block/CU, 4 waves:
// 1 wave/SIMD left the x-stream latency-exposed; R3's 4/CU over-split the
// 3125 tiles). ~3 tiles/wave-slot amortizes the 32KB W-staging.
// R4: k_final fused via last-arriver (acq-rel counter; pattern validated in
// R2 mega run, absmax 0.0): saves a launch gap + 1-block kernel latency.
__global__ __launch_bounds__(256, 2) void k_main(
    const float* __restrict__ x, const float* __restrict__ Wf,
    const float* __restrict__ bfeat, const float* __restrict__ w,
    float* __restrict__ vacc, unsigned* __restrict__ cnt,
    const float* __restrict__ Wg, const float* __restrict__ bg,
    const float* __restrict__ W1, const float* __restrict__ b1,
    const float* __restrict__ W2, const float* __restrict__ b2,
    float* __restrict__ out) {
  // B-fragments of W_feat, pre-swizzled: frag (kt,t), lane-contiguous 16B
  __shared__ __align__(16) short lW[32 * 64 * 8];   // 32 KB
  const int tid = threadIdx.x;
  for (int c = tid; c < 2048; c += 256) {           // c = (kt*8+t)*64 + lane
    int lane = c & 63, t = (c >> 6) & 7, kt = c >> 9;
    int h = t * 16 + (lane & 15);
    int dbase = kt * 32 + (lane >> 4) * 8;
    short8 v;
#pragma unroll
    for (int j = 0; j < 8; ++j) v[j] = f2bf(Wf[(dbase + j) * HD + h]);
    *(short8*)&lW[c * 8] = v;
  }
  __syncthreads();

  const int lane = tid & 63;
  const int wave = tid >> 6;
  const int col  = lane & 15;
  const int quad = lane >> 4;
  const int b    = blockIdx.y;

  float bias[8];
#pragma unroll
  for (int t = 0; t < 8; ++t) bias[t] = bfeat[t * 16 + col];

  float pv[8];
#pragma unroll
  for (int t = 0; t < 8; ++t) pv[t] = 0.f;

  const float* xb = x + (size_t)b * N_NODES * HD;
  for (int tile = blockIdx.x * 4 + wave; tile < NTILES; tile += gridDim.x * 4) {
    const int n0 = tile * 16;
    const float* xr = xb + (size_t)(n0 + col) * HD + quad * 8;  // A row = col
    floatx4 acc[8] = {};
#pragma unroll
    for (int kt = 0; kt < 4; ++kt) {
      floatx4 xlo = *(const floatx4*)(xr + kt * 32);
      floatx4 xhi = *(const floatx4*)(xr + kt * 32 + 4);
      short8 a;
#pragma unroll
      for (int j = 0; j < 4; ++j) { a[j] = f2bf(xlo[j]); a[j + 4] = f2bf(xhi[j]); }
#pragma unroll
      for (int t = 0; t < 8; ++t) {
        short8 bf = *(const short8*)&lW[((kt * 8 + t) * 64 + lane) * 8];
        acc[t] = __builtin_amdgcn_mfma_f32_16x16x32_bf16(a, bf, acc[t], 0, 0, 0);
      }
    }
    floatx4 w4 = *(const floatx4*)&w[n0 + quad * 4];  // D rows = quad*4 + r
#pragma unroll
    for (int t = 0; t < 8; ++t) {
#pragma unroll
      for (int r = 0; r < 4; ++r) {
        float y = acc[t][r] + bias[t];
        pv[t] += fmaxf(y, 0.f) * w4[r];
      }
    }
  }

  // cross-wave LDS reduce, then ONE atomic per (b,h) per block
  __syncthreads();                     // all lW reads done; reuse as scratch
  float* red = (float*)lW;             // need 4*128 floats
#pragma unroll
  for (int t = 0; t < 8; ++t) {
    float v = pv[t];
    v += __shfl_xor(v, 32, 64);
    v += __shfl_xor(v, 16, 64);
    if (quad == 0) red[wave * 128 + t * 16 + col] = v;
  }
  __syncthreads();
  if (tid < 128) {
    float v = red[tid] + red[128 + tid] + red[256 + tid] + red[384 + tid];
    atomicAdd(&vacc[b * HD + tid], v);
  }

  // ---- last-arriving block runs the head; everyone else exits ----
  __syncthreads();                     // block's vacc atomics drained
  __shared__ int lastFlag;
  if (tid == 0) {
    unsigned old = __hip_atomic_fetch_add(cnt, 1u, __ATOMIC_ACQ_REL,
                                          __HIP_MEMORY_SCOPE_AGENT);
    lastFlag = (old == gridDim.x * gridDim.y - 1) ? 1 : 0;
  }
  __syncthreads();
  if (!lastFlag) return;
  __threadfence();                     // see all blocks' vacc atomics

  {
    float* pooled = (float*)lW;          // 2*128 floats (reuse LDS)
    float* zz     = pooled + 2 * HD;     // 2*128 floats
    float* rf     = zz + 2 * HD;         // 256 floats
    const int hb = tid >> 7, h = tid & 127;
    float acc = 0.f;
    for (int k = 0; k < HD; ++k) acc += vacc[hb * HD + k] * Wg[k * HD + h];
    pooled[hb * HD + h] = acc * (1.0f / N_NODES) + bg[h];
    __syncthreads();
    acc = 0.f;
    for (int k = 0; k < HD; ++k) acc += pooled[hb * HD + k] * W1[k * HD + h];
    zz[hb * HD + h] = fmaxf(acc + b1[h], 0.f);
    __syncthreads();
    rf[tid] = zz[hb * HD + h] * W2[h];
    __syncthreads();
    if (tid < 2) {
      float s = 0.f;
      for (int k = 0; k < HD; ++k) s += rf[tid * HD + k];
      out[tid] = s + b2[0];
    }
  }
}

extern "C" void kernel_launch(void* const* d_in, const int* in_sizes, int n_in,
                              void* d_out, int out_size, void* d_ws, size_t ws_size,
                              hipStream_t stream) {
  const float* x  = (const float*)d_in[0];
  const int*   ei = (const int*)d_in[1];
  const float* Wf = (const float*)d_in[2];
  const float* bf = (const float*)d_in[3];
  const float* Wg = (const float*)d_in[4];
  const float* bg = (const float*)d_in[5];
  const float* W1 = (const float*)d_in[6];
  const float* b1 = (const float*)d_in[7];
  const float* W2 = (const float*)d_in[8];
  const float* b2 = (const float*)d_in[9];
  float* out = (float*)d_out;

  const int E = in_sizes[1] / 2;
  const int* src = ei;
  const int* dst = ei + E;
  const int perSlice = (E + NSLICE - 1) / NSLICE;

  char* ws = (char*)d_ws;
  const size_t partialB = (size_t)NSLICE * N_NODES * 4;          // 12.8 MB
  const size_t nodeB    = (N_NODES * 4 + 255) & ~(size_t)255;    // 200192 B
  const size_t needed   = partialB + 2 * nodeB + 1024 + 256;

  if (ws_size >= needed) {
    float*    partial = (float*)ws;
    float*    dinv    = (float*)(ws + partialB);
    float*    w       = (float*)(ws + partialB + nodeB);
    float*    vacc    = (float*)(ws + partialB + 2 * nodeB);
    unsigned* cnt     = (unsigned*)(ws + partialB + 2 * nodeB + 1024);

    dim3 sg(NSLICE, N_NODES / NQUART);   // 64 x 4 = 256 blocks
    k_scatter<false><<<sg, 1024, 0, stream>>>(dst, nullptr, nullptr, partial, E, perSlice);
    k_merge_deg<<<(N_NODES + 255) / 256, 256, 0, stream>>>(partial, dinv);
    k_scatter<true><<<sg, 1024, 0, stream>>>(src, dst, dinv, partial, E, perSlice);
    k_merge_w<<<(N_NODES + 255) / 256, 256, 0, stream>>>(partial, dinv, w, vacc, cnt);
    dim3 grid(256, 2);                   // 512 blocks, 2/CU, 8 waves/CU
    k_main<<<grid, 256, 0, stream>>>(x, Wf, bf, w, vacc, cnt,
                                     Wg, bg, W1, b1, W2, b2, out);
  } else {
    // fallback: device-atomic path
    int*      deg  = (int*)ws;
    float*    s    = (float*)(ws + nodeB);
    float*    vacc = (float*)(ws + 2 * nodeB);
    unsigned* cnt  = (unsigned*)(ws + 2 * nodeB + 1024);
    k_init<<<(N_NODES + 255) / 256, 256, 0, stream>>>(deg, s, vacc, cnt);
    k_deg_at<<<(E + 255) / 256, 256, 0, stream>>>(dst, deg, E);
    k_s_at<<<(E + 255) / 256, 256, 0, stream>>>(src, dst, deg, s, E);
    k_w_at<<<(N_NODES + 255) / 256, 256, 0, stream>>>(deg, s);
    dim3 grid(256, 2);
    k_main<<<grid, 256, 0, stream>>>(x, Wf, bf, s, vacc, cnt,
                                     Wg, bg, W1, b1, W2, b2, out);
  }
  (void)n_in; (void)out_size; (void)ws_size;
}

// Round 5
// 157.319 us; speedup vs baseline: 1.6232x; 1.0115x over previous
//
#include <hip/hip_runtime.h>
#include <hip/hip_bf16.h>

#define N_NODES 50000
#define HD 128
#define NTILES (N_NODES / 16)   // 3125, exact
#define NSLICE 64               // edge slices for privatized scatter
#define NQUART 12500            // nodes per LDS quarter (50 KB f32 bins)

using short8  = __attribute__((ext_vector_type(8))) short;   // 8 x bf16 bits
using floatx4 = __attribute__((ext_vector_type(4))) float;

__device__ __forceinline__ short f2bf(float f) {
  union { float fp; unsigned u; } un; un.fp = f;
  unsigned u = un.u + 0x7fffu + ((un.u >> 16) & 1u);   // RNE
  return (short)(u >> 16);
}

// =======================  fast edge phase (no device atomics)  ==============
// R0-verbatim. partial[s][n] accumulates per-slice sums; block (slice,quarter)
// owns 12500-node LDS bins and writes them back non-atomically.
template <bool GATHER>
__global__ __launch_bounds__(1024) void k_scatter(
    const int* __restrict__ keys, const int* __restrict__ other,
    const float* __restrict__ dinv, float* __restrict__ partial,
    int E, int perSlice) {
  __shared__ __align__(16) float bins[NQUART];
  const int tid = threadIdx.x;
  for (int i = tid; i < NQUART / 4; i += 1024)
    ((float4*)bins)[i] = make_float4(0.f, 0.f, 0.f, 0.f);
  __syncthreads();

  const int slice = blockIdx.x;
  const int base  = blockIdx.y * NQUART;
  const int e0 = slice * perSlice;
  const int e1 = min(e0 + perSlice, E);
  for (int e = e0 + tid; e < e1; e += 1024) {
    int k = keys[e];
    if ((unsigned)(k - base) < (unsigned)NQUART) {
      float v = GATHER ? dinv[other[e]] : 1.0f;
      atomicAdd(&bins[k - base], v);           // ds_add_f32, LDS-local
    }
  }
  __syncthreads();

  float* out = partial + (size_t)slice * N_NODES + base;
  for (int i = tid; i < NQUART / 4; i += 1024)
    ((float4*)out)[i] = ((const float4*)bins)[i];
}

// dinv[n] = rsqrt(1 + sum_s partial[s][n])      (self-loop -> +1)
__global__ void k_merge_deg(const float* __restrict__ partial,
                            float* __restrict__ dinv) {
  int n = blockIdx.x * 256 + threadIdx.x;
  if (n >= N_NODES) return;
  float s = 1.0f;
  for (int sl = 0; sl < NSLICE; ++sl) s += partial[(size_t)sl * N_NODES + n];
  dinv[n] = rsqrtf(s);
}

// w[n] = dinv[n] * (sum_s partial[s][n] + dinv[n]);  also zero vacc
__global__ void k_merge_w(const float* __restrict__ partial,
                          const float* __restrict__ dinv,
                          float* __restrict__ w, float* __restrict__ vacc) {
  int n = blockIdx.x * 256 + threadIdx.x;
  if (n < 2 * HD) vacc[n] = 0.f;
  if (n >= N_NODES) return;
  float s = 0.0f;
  for (int sl = 0; sl < NSLICE; ++sl) s += partial[(size_t)sl * N_NODES + n];
  float dv = dinv[n];
  w[n] = dv * (s + dv);
}

// =======================  fallback edge phase (device atomics)  =============
__global__ void k_init(int* __restrict__ deg, float* __restrict__ s,
                       float* __restrict__ vacc) {
  int i = blockIdx.x * 256 + threadIdx.x;
  if (i < N_NODES) { deg[i] = 1; s[i] = 0.f; }
  if (i < 2 * HD) vacc[i] = 0.f;
}
__global__ void k_deg_at(const int* __restrict__ dst, int* __restrict__ deg, int E) {
  int i = blockIdx.x * 256 + threadIdx.x;
  if (i < E) atomicAdd(&deg[dst[i]], 1);
}
__global__ void k_s_at(const int* __restrict__ src, const int* __restrict__ dst,
                       const int* __restrict__ deg, float* __restrict__ s, int E) {
  int i = blockIdx.x * 256 + threadIdx.x;
  if (i < E) {
    float dv = rsqrtf((float)deg[dst[i]]);
    atomicAdd(&s[src[i]], dv);
  }
}
__global__ void k_w_at(const int* __restrict__ deg, float* __restrict__ s) {
  int i = blockIdx.x * 256 + threadIdx.x;
  if (i < N_NODES) {
    float dv = rsqrtf((float)deg[i]);
    s[i] = dv * (s[i] + dv);
  }
}

// ---- main: vacc[b,h] = sum_n w[n] * relu(x[b,n,:] @ W_feat + b_feat)[h] ----
// R5: manual 2-stage software pipeline. The compiler cannot hoist next-tile
// loads past the `tile < NTILES` check (R4 counters: VALUBusy 5.5%, MfmaUtil
// 2.2%, HBM 8% -> pure latency stall). Wave-uniform guards, ping-pong regs.
#define LOADX(dst, ptr) do {                                        \
    _Pragma("unroll") for (int kk = 0; kk < 4; ++kk) {              \
      dst##0[kk] = *(const floatx4*)((ptr) + kk * 32);              \
      dst##1[kk] = *(const floatx4*)((ptr) + kk * 32 + 4);          \
    } } while (0)

#define COMPUTE(X, W4) do {                                         \
    floatx4 acc[8] = {};                                            \
    _Pragma("unroll") for (int kt = 0; kt < 4; ++kt) {              \
      short8 a;                                                     \
      _Pragma("unroll") for (int j = 0; j < 4; ++j) {               \
        a[j] = f2bf(X##0[kt][j]); a[j + 4] = f2bf(X##1[kt][j]); }   \
      _Pragma("unroll") for (int t = 0; t < 8; ++t) {               \
        short8 bfr = *(const short8*)&lW[((kt * 8 + t) * 64 + lane) * 8]; \
        acc[t] = __builtin_amdgcn_mfma_f32_16x16x32_bf16(a, bfr, acc[t], 0, 0, 0); } } \
    _Pragma("unroll") for (int t = 0; t < 8; ++t)                   \
      _Pragma("unroll") for (int r = 0; r < 4; ++r) {               \
        float y = acc[t][r] + bias[t];                              \
        pv[t] += fmaxf(y, 0.f) * (W4)[r]; } } while (0)

__global__ __launch_bounds__(256, 2) void k_main(
    const float* __restrict__ x, const float* __restrict__ Wf,
    const float* __restrict__ bfeat, const float* __restrict__ w,
    float* __restrict__ vacc) {
  // B-fragments of W_feat, pre-swizzled: frag (kt,t), lane-contiguous 16B
  __shared__ __align__(16) short lW[32 * 64 * 8];   // 32 KB
  const int tid = threadIdx.x;
  for (int c = tid; c < 2048; c += 256) {           // c = (kt*8+t)*64 + lane
    int lane = c & 63, t = (c >> 6) & 7, kt = c >> 9;
    int h = t * 16 + (lane & 15);
    int dbase = kt * 32 + (lane >> 4) * 8;
    short8 v;
#pragma unroll
    for (int j = 0; j < 8; ++j) v[j] = f2bf(Wf[(dbase + j) * HD + h]);
    *(short8*)&lW[c * 8] = v;
  }
  __syncthreads();

  const int lane = tid & 63;
  const int wave = tid >> 6;
  const int col  = lane & 15;
  const int quad = lane >> 4;
  const int b    = blockIdx.y;

  float bias[8];
#pragma unroll
  for (int t = 0; t < 8; ++t) bias[t] = bfeat[t * 16 + col];

  float pv[8];
#pragma unroll
  for (int t = 0; t < 8; ++t) pv[t] = 0.f;

  const float* xbase = x + (size_t)b * N_NODES * HD;
#define XPTR(t) (xbase + (size_t)((t) * 16 + col) * HD + quad * 8)

  const int stride = gridDim.x * 4;      // 1024 wave-slots per batch
  const int t0 = blockIdx.x * 4 + wave;  // < 1024 < NTILES always

  floatx4 xA0[4], xA1[4], xB0[4], xB1[4];
  floatx4 wA = {}, wB = {};
  LOADX(xA, XPTR(t0));
  wA = *(const floatx4*)&w[t0 * 16 + quad * 4];
  for (int tile = t0; tile < NTILES; tile += 2 * stride) {
    const int t1 = tile + stride, t2 = tile + 2 * stride;
    if (t1 < NTILES) {                   // wave-uniform branch
      LOADX(xB, XPTR(t1));
      wB = *(const floatx4*)&w[t1 * 16 + quad * 4];
    }
    COMPUTE(xA, wA);                     // waits only on xA's loads
    if (t2 < NTILES) {
      LOADX(xA, XPTR(t2));
      wA = *(const floatx4*)&w[t2 * 16 + quad * 4];
    }
    if (t1 < NTILES) COMPUTE(xB, wB);
  }

  // cross-wave LDS reduce, then ONE atomic per (b,h) per block
  __syncthreads();                     // all lW reads done; reuse as scratch
  float* red = (float*)lW;             // need 4*128 floats
#pragma unroll
  for (int t = 0; t < 8; ++t) {
    float v = pv[t];
    v += __shfl_xor(v, 32, 64);
    v += __shfl_xor(v, 16, 64);
    if (quad == 0) red[wave * 128 + t * 16 + col] = v;
  }
  __syncthreads();
  if (tid < 128) {
    float v = red[tid] + red[128 + tid] + red[256 + tid] + red[384 + tid];
    atomicAdd(&vacc[b * HD + tid], v);
  }
}

// ---- tiny head, latency-aware rewrite ----
// R5: the old 256-thread head was 2x 128-deep serial-batch GEMVs on COLD
// Wg/W1 (evicted by the 256MB workspace fill) ~ 8-12 us. 1024 threads,
// 4-way k-split: 32 independent unrolled loads/thread -> ~2 cold round-trips.
__global__ __launch_bounds__(1024) void k_final(
    const float* __restrict__ vacc, const float* __restrict__ Wg,
    const float* __restrict__ bg, const float* __restrict__ W1,
    const float* __restrict__ b1, const float* __restrict__ W2,
    const float* __restrict__ b2, float* __restrict__ out) {
  __shared__ float part[4][256];
  __shared__ float pooled[2][HD];
  __shared__ float z[2][HD];
  __shared__ float red[256];
  const int tid = threadIdx.x;
  const int kq = tid >> 8;              // k-quarter 0..3
  const int pr = tid & 255;             // (b,h) pair
  const int b  = pr >> 7, h = pr & 127;
  {
    const int k0 = kq * 32;
    float acc = 0.f;
#pragma unroll
    for (int k = 0; k < 32; ++k)
      acc += vacc[b * HD + k0 + k] * Wg[(k0 + k) * HD + h];
    part[kq][pr] = acc;
  }
  __syncthreads();
  if (tid < 256) {
    float acc = part[0][tid] + part[1][tid] + part[2][tid] + part[3][tid];
    pooled[b][h] = acc * (1.0f / N_NODES) + bg[h];
  }
  __syncthreads();
  {
    const int k0 = kq * 32;
    float acc = 0.f;
#pragma unroll
    for (int k = 0; k < 32; ++k)
      acc += pooled[b][k0 + k] * W1[(k0 + k) * HD + h];
    part[kq][pr] = acc;
  }
  __syncthreads();
  if (tid < 256) {
    float acc = part[0][tid] + part[1][tid] + part[2][tid] + part[3][tid];
    z[b][h] = fmaxf(acc + b1[h], 0.f);
  }
  __syncthreads();
  if (tid < 256) red[tid] = z[b][h] * W2[h];
  __syncthreads();
  if (tid < 2) {
    float s = 0.f;
    for (int k = 0; k < HD; ++k) s += red[tid * HD + k];
    out[tid] = s + b2[0];
  }
}

extern "C" void kernel_launch(void* const* d_in, const int* in_sizes, int n_in,
                              void* d_out, int out_size, void* d_ws, size_t ws_size,
                              hipStream_t stream) {
  const float* x  = (const float*)d_in[0];
  const int*   ei = (const int*)d_in[1];
  const float* Wf = (const float*)d_in[2];
  const float* bf = (const float*)d_in[3];
  const float* Wg = (const float*)d_in[4];
  const float* bg = (const float*)d_in[5];
  const float* W1 = (const float*)d_in[6];
  const float* b1 = (const float*)d_in[7];
  const float* W2 = (const float*)d_in[8];
  const float* b2 = (const float*)d_in[9];
  float* out = (float*)d_out;

  const int E = in_sizes[1] / 2;
  const int* src = ei;
  const int* dst = ei + E;
  const int perSlice = (E + NSLICE - 1) / NSLICE;

  char* ws = (char*)d_ws;
  const size_t partialB = (size_t)NSLICE * N_NODES * 4;          // 12.8 MB
  const size_t nodeB    = (N_NODES * 4 + 255) & ~(size_t)255;    // 200192 B
  const size_t needed   = partialB + 2 * nodeB + 1024;

  if (ws_size >= needed) {
    float* partial = (float*)ws;
    float* dinv    = (float*)(ws + partialB);
    float* w       = (float*)(ws + partialB + nodeB);
    float* vacc    = (float*)(ws + partialB + 2 * nodeB);

    dim3 sg(NSLICE, N_NODES / NQUART);   // 64 x 4 = 256 blocks
    k_scatter<false><<<sg, 1024, 0, stream>>>(dst, nullptr, nullptr, partial, E, perSlice);
    k_merge_deg<<<(N_NODES + 255) / 256, 256, 0, stream>>>(partial, dinv);
    k_scatter<true><<<sg, 1024, 0, stream>>>(src, dst, dinv, partial, E, perSlice);
    k_merge_w<<<(N_NODES + 255) / 256, 256, 0, stream>>>(partial, dinv, w, vacc);
    dim3 grid(256, 2);                   // 512 blocks, 2/CU, 8 waves/CU
    k_main<<<grid, 256, 0, stream>>>(x, Wf, bf, w, vacc);
    k_final<<<1, 1024, 0, stream>>>(vacc, Wg, bg, W1, b1, W2, b2, out);
  } else {
    // fallback: device-atomic path
    int*   deg  = (int*)ws;
    float* s    = (float*)(ws + nodeB);
    float* vacc = (float*)(ws + 2 * nodeB);
    k_init<<<(N_NODES + 255) / 256, 256, 0, stream>>>(deg, s, vacc);
    k_deg_at<<<(E + 255) / 256, 256, 0, stream>>>(dst, deg, E);
    k_s_at<<<(E + 255) / 256, 256, 0, stream>>>(src, dst, deg, s, E);
    k_w_at<<<(N_NODES + 255) / 256, 256, 0, stream>>>(deg, s);
    dim3 grid(256, 2);
    k_main<<<grid, 256, 0, stream>>>(x, Wf, bf, s, vacc);
    k_final<<<1, 1024, 0, stream>>>(vacc, Wg, bg, W1, b1, W2, b2, out);
  }
  (void)n_in; (void)out_size; (void)ws_size;
}

// Round 6
// 151.480 us; speedup vs baseline: 1.6857x; 1.0386x over previous
//
#include <hip/hip_runtime.h>
#include <hip/hip_bf16.h>

#define N_NODES 50000
#define HD 128
#define NTILES (N_NODES / 16)   // 3125, exact
#define NSLICE 64               // edge slices for privatized scatter
#define NQUART 12500            // nodes per LDS quarter (50 KB f32 bins)
#define NG 32                   // vacc privatization groups: 8-deep atomic chains

using short8  = __attribute__((ext_vector_type(8))) short;   // 8 x bf16 bits
using floatx4 = __attribute__((ext_vector_type(4))) float;

__device__ __forceinline__ short f2bf(float f) {
  union { float fp; unsigned u; } un; un.fp = f;
  unsigned u = un.u + 0x7fffu + ((un.u >> 16) & 1u);   // RNE
  return (short)(u >> 16);
}

// =======================  fast edge phase (no device atomics)  ==============
// R0-verbatim. partial[s][n] accumulates per-slice sums; block (slice,quarter)
// owns 12500-node LDS bins and writes them back non-atomically.
template <bool GATHER>
__global__ __launch_bounds__(1024) void k_scatter(
    const int* __restrict__ keys, const int* __restrict__ other,
    const float* __restrict__ dinv, float* __restrict__ partial,
    int E, int perSlice) {
  __shared__ __align__(16) float bins[NQUART];
  const int tid = threadIdx.x;
  for (int i = tid; i < NQUART / 4; i += 1024)
    ((float4*)bins)[i] = make_float4(0.f, 0.f, 0.f, 0.f);
  __syncthreads();

  const int slice = blockIdx.x;
  const int base  = blockIdx.y * NQUART;
  const int e0 = slice * perSlice;
  const int e1 = min(e0 + perSlice, E);
  for (int e = e0 + tid; e < e1; e += 1024) {
    int k = keys[e];
    if ((unsigned)(k - base) < (unsigned)NQUART) {
      float v = GATHER ? dinv[other[e]] : 1.0f;
      atomicAdd(&bins[k - base], v);           // ds_add_f32, LDS-local
    }
  }
  __syncthreads();

  float* out = partial + (size_t)slice * N_NODES + base;
  for (int i = tid; i < NQUART / 4; i += 1024)
    ((float4*)out)[i] = ((const float4*)bins)[i];
}

// dinv[n] = rsqrt(1 + sum_s partial[s][n])      (self-loop -> +1)
__global__ void k_merge_deg(const float* __restrict__ partial,
                            float* __restrict__ dinv) {
  int n = blockIdx.x * 256 + threadIdx.x;
  if (n >= N_NODES) return;
  float s = 1.0f;
  for (int sl = 0; sl < NSLICE; ++sl) s += partial[(size_t)sl * N_NODES + n];
  dinv[n] = rsqrtf(s);
}

// w[n] = dinv[n] * (sum_s partial[s][n] + dinv[n]);  also zero vaccp (32 KB)
__global__ void k_merge_w(const float* __restrict__ partial,
                          const float* __restrict__ dinv,
                          float* __restrict__ w, float* __restrict__ vaccp) {
  int n = blockIdx.x * 256 + threadIdx.x;
  if (n < NG * 2 * HD) vaccp[n] = 0.f;
  if (n >= N_NODES) return;
  float s = 0.0f;
  for (int sl = 0; sl < NSLICE; ++sl) s += partial[(size_t)sl * N_NODES + n];
  float dv = dinv[n];
  w[n] = dv * (s + dv);
}

// =======================  fallback edge phase (device atomics)  =============
__global__ void k_init(int* __restrict__ deg, float* __restrict__ s,
                       float* __restrict__ vaccp) {
  int i = blockIdx.x * 256 + threadIdx.x;
  if (i < N_NODES) { deg[i] = 1; s[i] = 0.f; }
  if (i < NG * 2 * HD) vaccp[i] = 0.f;
}
__global__ void k_deg_at(const int* __restrict__ dst, int* __restrict__ deg, int E) {
  int i = blockIdx.x * 256 + threadIdx.x;
  if (i < E) atomicAdd(&deg[dst[i]], 1);
}
__global__ void k_s_at(const int* __restrict__ src, const int* __restrict__ dst,
                       const int* __restrict__ deg, float* __restrict__ s, int E) {
  int i = blockIdx.x * 256 + threadIdx.x;
  if (i < E) {
    float dv = rsqrtf((float)deg[dst[i]]);
    atomicAdd(&s[src[i]], dv);
  }
}
__global__ void k_w_at(const int* __restrict__ deg, float* __restrict__ s) {
  int i = blockIdx.x * 256 + threadIdx.x;
  if (i < N_NODES) {
    float dv = rsqrtf((float)deg[i]);
    s[i] = dv * (s[i] + dv);
  }
}

// ---- main: vaccp[g,b,h] += sum_n w[n] * relu(x[b,n,:] @ W_feat + b_feat)[h]
// R6: ONE change vs R5 — privatize the output atomics into NG=32 groups.
// Theory (fits R0/R2/R3/R4/R5): same-address device-scope f32 RMWs serialize
// at ~150-200ns each at the cross-XCD coherence point; 256 blocks arriving
// together -> ~43us chain = k_main's hidden cost (and the mega-kernel's
// barrier disaster). g=bx&31 -> 8-deep chains (~1.4us).
#define LOADX(dst, ptr) do {                                        \
    _Pragma("unroll") for (int kk = 0; kk < 4; ++kk) {              \
      dst##0[kk] = *(const floatx4*)((ptr) + kk * 32);              \
      dst##1[kk] = *(const floatx4*)((ptr) + kk * 32 + 4);          \
    } } while (0)

#define COMPUTE(X, W4) do {                                         \
    floatx4 acc[8] = {};                                            \
    _Pragma("unroll") for (int kt = 0; kt < 4; ++kt) {              \
      short8 a;                                                     \
      _Pragma("unroll") for (int j = 0; j < 4; ++j) {               \
        a[j] = f2bf(X##0[kt][j]); a[j + 4] = f2bf(X##1[kt][j]); }   \
      _Pragma("unroll") for (int t = 0; t < 8; ++t) {               \
        short8 bfr = *(const short8*)&lW[((kt * 8 + t) * 64 + lane) * 8]; \
        acc[t] = __builtin_amdgcn_mfma_f32_16x16x32_bf16(a, bfr, acc[t], 0, 0, 0); } } \
    _Pragma("unroll") for (int t = 0; t < 8; ++t)                   \
      _Pragma("unroll") for (int r = 0; r < 4; ++r) {               \
        float y = acc[t][r] + bias[t];                              \
        pv[t] += fmaxf(y, 0.f) * (W4)[r]; } } while (0)

__global__ __launch_bounds__(256, 2) void k_main(
    const float* __restrict__ x, const float* __restrict__ Wf,
    const float* __restrict__ bfeat, const float* __restrict__ w,
    float* __restrict__ vaccp) {
  // B-fragments of W_feat, pre-swizzled: frag (kt,t), lane-contiguous 16B
  __shared__ __align__(16) short lW[32 * 64 * 8];   // 32 KB
  const int tid = threadIdx.x;
  for (int c = tid; c < 2048; c += 256) {           // c = (kt*8+t)*64 + lane
    int lane = c & 63, t = (c >> 6) & 7, kt = c >> 9;
    int h = t * 16 + (lane & 15);
    int dbase = kt * 32 + (lane >> 4) * 8;
    short8 v;
#pragma unroll
    for (int j = 0; j < 8; ++j) v[j] = f2bf(Wf[(dbase + j) * HD + h]);
    *(short8*)&lW[c * 8] = v;
  }
  __syncthreads();

  const int lane = tid & 63;
  const int wave = tid >> 6;
  const int col  = lane & 15;
  const int quad = lane >> 4;
  const int b    = blockIdx.y;
  const int g    = blockIdx.x & (NG - 1);

  float bias[8];
#pragma unroll
  for (int t = 0; t < 8; ++t) bias[t] = bfeat[t * 16 + col];

  float pv[8];
#pragma unroll
  for (int t = 0; t < 8; ++t) pv[t] = 0.f;

  const float* xbase = x + (size_t)b * N_NODES * HD;
#define XPTR(t) (xbase + (size_t)((t) * 16 + col) * HD + quad * 8)

  const int stride = gridDim.x * 4;      // 1024 wave-slots per batch
  const int t0 = blockIdx.x * 4 + wave;  // < 1024 < NTILES always

  floatx4 xA0[4], xA1[4], xB0[4], xB1[4];
  floatx4 wA = {}, wB = {};
  LOADX(xA, XPTR(t0));
  wA = *(const floatx4*)&w[t0 * 16 + quad * 4];
  for (int tile = t0; tile < NTILES; tile += 2 * stride) {
    const int t1 = tile + stride, t2 = tile + 2 * stride;
    if (t1 < NTILES) {                   // wave-uniform branch
      LOADX(xB, XPTR(t1));
      wB = *(const floatx4*)&w[t1 * 16 + quad * 4];
    }
    COMPUTE(xA, wA);                     // waits only on xA's loads
    if (t2 < NTILES) {
      LOADX(xA, XPTR(t2));
      wA = *(const floatx4*)&w[t2 * 16 + quad * 4];
    }
    if (t1 < NTILES) COMPUTE(xB, wB);
  }

  // cross-wave LDS reduce, then ONE atomic per (g,b,h) per block (8-deep)
  __syncthreads();                     // all lW reads done; reuse as scratch
  float* red = (float*)lW;             // need 4*128 floats
#pragma unroll
  for (int t = 0; t < 8; ++t) {
    float v = pv[t];
    v += __shfl_xor(v, 32, 64);
    v += __shfl_xor(v, 16, 64);
    if (quad == 0) red[wave * 128 + t * 16 + col] = v;
  }
  __syncthreads();
  if (tid < 128) {
    float v = red[tid] + red[128 + tid] + red[256 + tid] + red[384 + tid];
    atomicAdd(&vaccp[(g * 2 + b) * HD + tid], v);
  }
}

// ---- tiny head: 32-group pre-sum, then latency-aware 4-way k-split GEMVs ----
__global__ __launch_bounds__(1024) void k_final(
    const float* __restrict__ vaccp, const float* __restrict__ Wg,
    const float* __restrict__ bg, const float* __restrict__ W1,
    const float* __restrict__ b1, const float* __restrict__ W2,
    const float* __restrict__ b2, float* __restrict__ out) {
  __shared__ float part[4][256];
  __shared__ float vsum[256];
  __shared__ float pooled[2][HD];
  __shared__ float z[2][HD];
  __shared__ float red[256];
  const int tid = threadIdx.x;
  const int kq = tid >> 8;              // quarter 0..3
  const int pr = tid & 255;             // (b,h) pair
  const int b  = pr >> 7, h = pr & 127;
  {
    float acc = 0.f;                    // sum 8 of the 32 groups
#pragma unroll
    for (int j = 0; j < 8; ++j)
      acc += vaccp[(kq * 8 + j) * 2 * HD + pr];
    part[kq][pr] = acc;
  }
  __syncthreads();
  if (tid < 256)
    vsum[tid] = part[0][tid] + part[1][tid] + part[2][tid] + part[3][tid];
  __syncthreads();
  {
    const int k0 = kq * 32;
    float acc = 0.f;
#pragma unroll
    for (int k = 0; k < 32; ++k)
      acc += vsum[b * HD + k0 + k] * Wg[(k0 + k) * HD + h];
    part[kq][pr] = acc;
  }
  __syncthreads();
  if (tid < 256) {
    float acc = part[0][tid] + part[1][tid] + part[2][tid] + part[3][tid];
    pooled[b][h] = acc * (1.0f / N_NODES) + bg[h];
  }
  __syncthreads();
  {
    const int k0 = kq * 32;
    float acc = 0.f;
#pragma unroll
    for (int k = 0; k < 32; ++k)
      acc += pooled[b][k0 + k] * W1[(k0 + k) * HD + h];
    part[kq][pr] = acc;
  }
  __syncthreads();
  if (tid < 256) {
    float acc = part[0][tid] + part[1][tid] + part[2][tid] + part[3][tid];
    z[b][h] = fmaxf(acc + b1[h], 0.f);
  }
  __syncthreads();
  if (tid < 256) red[tid] = z[b][h] * W2[h];
  __syncthreads();
  if (tid < 2) {
    float s = 0.f;
    for (int k = 0; k < HD; ++k) s += red[tid * HD + k];
    out[tid] = s + b2[0];
  }
}

extern "C" void kernel_launch(void* const* d_in, const int* in_sizes, int n_in,
                              void* d_out, int out_size, void* d_ws, size_t ws_size,
                              hipStream_t stream) {
  const float* x  = (const float*)d_in[0];
  const int*   ei = (const int*)d_in[1];
  const float* Wf = (const float*)d_in[2];
  const float* bf = (const float*)d_in[3];
  const float* Wg = (const float*)d_in[4];
  const float* bg = (const float*)d_in[5];
  const float* W1 = (const float*)d_in[6];
  const float* b1 = (const float*)d_in[7];
  const float* W2 = (const float*)d_in[8];
  const float* b2 = (const float*)d_in[9];
  float* out = (float*)d_out;

  const int E = in_sizes[1] / 2;
  const int* src = ei;
  const int* dst = ei + E;
  const int perSlice = (E + NSLICE - 1) / NSLICE;

  char* ws = (char*)d_ws;
  const size_t partialB = (size_t)NSLICE * N_NODES * 4;          // 12.8 MB
  const size_t nodeB    = (N_NODES * 4 + 255) & ~(size_t)255;    // 200192 B
  const size_t vaccB    = NG * 2 * HD * 4;                       // 32 KB
  const size_t needed   = partialB + 2 * nodeB + vaccB;

  if (ws_size >= needed) {
    float* partial = (float*)ws;
    float* dinv    = (float*)(ws + partialB);
    float* w       = (float*)(ws + partialB + nodeB);
    float* vaccp   = (float*)(ws + partialB + 2 * nodeB);

    dim3 sg(NSLICE, N_NODES / NQUART);   // 64 x 4 = 256 blocks
    k_scatter<false><<<sg, 1024, 0, stream>>>(dst, nullptr, nullptr, partial, E, perSlice);
    k_merge_deg<<<(N_NODES + 255) / 256, 256, 0, stream>>>(partial, dinv);
    k_scatter<true><<<sg, 1024, 0, stream>>>(src, dst, dinv, partial, E, perSlice);
    k_merge_w<<<(N_NODES + 255) / 256, 256, 0, stream>>>(partial, dinv, w, vaccp);
    dim3 grid(256, 2);                   // 512 blocks, 2/CU, 8 waves/CU
    k_main<<<grid, 256, 0, stream>>>(x, Wf, bf, w, vaccp);
    k_final<<<1, 1024, 0, stream>>>(vaccp, Wg, bg, W1, b1, W2, b2, out);
  } else {
    // fallback: device-atomic path
    int*   deg   = (int*)ws;
    float* s     = (float*)(ws + nodeB);
    float* vaccp = (float*)(ws + 2 * nodeB);
    k_init<<<(N_NODES + 255) / 256, 256, 0, stream>>>(deg, s, vaccp);
    k_deg_at<<<(E + 255) / 256, 256, 0, stream>>>(dst, deg, E);
    k_s_at<<<(E + 255) / 256, 256, 0, stream>>>(src, dst, deg, s, E);
    k_w_at<<<(N_NODES + 255) / 256, 256, 0, stream>>>(deg, s);
    dim3 grid(256, 2);
    k_main<<<grid, 256, 0, stream>>>(x, Wf, bf, s, vaccp);
    k_final<<<1, 1024, 0, stream>>>(vaccp, Wg, bg, W1, b1, W2, b2, out);
  }
  (void)n_in; (void)out_size; (void)ws_size;
}